// Round 6
// baseline (15.785 us; speedup 1.0000x reference)
//
#include <hip/hip_runtime.h>

#define N 2048
#define BS 16
#define QG 512             // queries per k1 block (8 per lane)
#define NQG (N / QG)       // 4 query groups
#define TS 64              // targets per k1 block
#define NTS (N / TS)       // 32 target slices
#define WAVES 4
#define TPB (WAVES * 64)   // 256 threads
#define TPW (TS / WAVES)   // 16 targets per wave
#define QPL 8              // queries per lane

// ws layout: wsmin[b][ts][q] (BS*NTS*N floats = 4 MB), then ws2[128] partials.
// wsmin holds min_t(|t|^2 - 2*tf.t) over the block's 64-target slice;
// k2 adds |tf|^2 back before sqrt (min(c+x) = c + min(x)).

__global__ __launch_bounds__(TPB, 4) void addsloss_k1(
    const float* __restrict__ target,
    const float* __restrict__ mp,
    const int* __restrict__ idx,
    const float* __restrict__ H,
    float* __restrict__ wsmin)
{
    __shared__ float4 tlds[TS];           // (x, y, z, |t|^2)  1 KB
    __shared__ float  pmin[WAVES][QG];    // 8 KB

    const int bid  = blockIdx.x;
    const int b    = bid >> 7;        // / (NQG*NTS) = /128
    const int rem  = bid & 127;
    const int qg   = rem >> 5;        // / NTS
    const int ts   = rem & 31;        // % NTS
    const int tid  = threadIdx.x;
    const int wave = tid >> 6;
    const int lane = tid & 63;

    const int  cls = idx[b];
    const bool sym = (cls >= 0) && (cls <= 3);
    if (!sym) return;                 // non-sym handled entirely in k2

    const float* tb = target + (size_t)b * N * 3;
    const float* mb = mp     + (size_t)b * N * 3;
    const float* hb = H      + b * 16;

    // Stage 64 targets as (x,y,z,|t|^2).
    if (tid < TS) {
        const int t = ts * TS + tid;
        const float x = tb[t * 3 + 0];
        const float y = tb[t * 3 + 1];
        const float z = tb[t * 3 + 2];
        tlds[tid] = make_float4(x, y, z, x * x + y * y + z * z);
    }

    // 8 queries per lane; store -2*tf so the inner op is pure fma.
    float ngx[QPL], ngy[QPL], ngz[QPL];
    #pragma unroll
    for (int qi = 0; qi < QPL; ++qi) {
        const int q = qg * QG + qi * 64 + lane;
        const float m0 = mb[q * 3 + 0];
        const float m1 = mb[q * 3 + 1];
        const float m2 = mb[q * 3 + 2];
        ngx[qi] = -2.0f * (hb[0] * m0 + hb[1]  * m1 + hb[2]  * m2 + hb[3]);
        ngy[qi] = -2.0f * (hb[4] * m0 + hb[5]  * m1 + hb[6]  * m2 + hb[7]);
        ngz[qi] = -2.0f * (hb[8] * m0 + hb[9]  * m1 + hb[10] * m2 + hb[11]);
    }

    __syncthreads();

    // This wave scans targets [wave*16, wave*16+16); each read feeds 8 queries.
    const float4* t4 = &tlds[wave * TPW];

    float acc[QPL][4];
    #pragma unroll
    for (int qi = 0; qi < QPL; ++qi)
        #pragma unroll
        for (int ti = 0; ti < 4; ++ti) acc[qi][ti] = 3.4e38f;

    #pragma unroll
    for (int j = 0; j < TPW / 4; ++j) {
        const float4 T0 = t4[j * 4 + 0];
        const float4 T1 = t4[j * 4 + 1];
        const float4 T2 = t4[j * 4 + 2];
        const float4 T3 = t4[j * 4 + 3];
        #pragma unroll
        for (int qi = 0; qi < QPL; ++qi) {
            float h;
            h = T0.w; h = fmaf(ngx[qi], T0.x, h); h = fmaf(ngy[qi], T0.y, h);
            h = fmaf(ngz[qi], T0.z, h); acc[qi][0] = fminf(acc[qi][0], h);
            h = T1.w; h = fmaf(ngx[qi], T1.x, h); h = fmaf(ngy[qi], T1.y, h);
            h = fmaf(ngz[qi], T1.z, h); acc[qi][1] = fminf(acc[qi][1], h);
            h = T2.w; h = fmaf(ngx[qi], T2.x, h); h = fmaf(ngy[qi], T2.y, h);
            h = fmaf(ngz[qi], T2.z, h); acc[qi][2] = fminf(acc[qi][2], h);
            h = T3.w; h = fmaf(ngx[qi], T3.x, h); h = fmaf(ngy[qi], T3.y, h);
            h = fmaf(ngz[qi], T3.z, h); acc[qi][3] = fminf(acc[qi][3], h);
        }
    }

    #pragma unroll
    for (int qi = 0; qi < QPL; ++qi)
        pmin[wave][qi * 64 + lane] =
            fminf(fminf(acc[qi][0], acc[qi][1]), fminf(acc[qi][2], acc[qi][3]));
    __syncthreads();

    // Combine the 4 waves; write this slice's per-query partial min.
    float* wrow = wsmin + ((size_t)(b * NTS + ts)) * N + qg * QG;
    #pragma unroll
    for (int k = 0; k < QG / TPB; ++k) {
        const int i = k * TPB + tid;
        wrow[i] = fminf(fminf(pmin[0][i], pmin[1][i]),
                        fminf(pmin[2][i], pmin[3][i]));
    }
}

// K2: 128 blocks (8 per batch) x 256 threads, 1 query/thread.
// sym: min over 32 slice-mins (coalesced strided loads) + |tf|^2 + sqrt;
// non-sym: direct distance. Fixed-order block partial -> ws2[bid].
__global__ __launch_bounds__(256) void addsloss_k2(
    const float* __restrict__ target,
    const float* __restrict__ mp,
    const int* __restrict__ idx,
    const float* __restrict__ H,
    const float* __restrict__ wsmin,
    float* __restrict__ ws2)
{
    __shared__ float ps[4];
    const int bid  = blockIdx.x;
    const int b    = bid >> 3;
    const int part = bid & 7;
    const int tid  = threadIdx.x;
    const int wave = tid >> 6;
    const int lane = tid & 63;
    const int q    = part * 256 + tid;

    const int  cls = idx[b];
    const bool sym = (cls >= 0) && (cls <= 3);

    const float* tb = target + (size_t)b * N * 3;
    const float* mb = mp     + (size_t)b * N * 3;
    const float* hb = H      + b * 16;

    const float m0 = mb[q * 3 + 0];
    const float m1 = mb[q * 3 + 1];
    const float m2 = mb[q * 3 + 2];
    const float fx = hb[0] * m0 + hb[1]  * m1 + hb[2]  * m2 + hb[3];
    const float fy = hb[4] * m0 + hb[5]  * m1 + hb[6]  * m2 + hb[7];
    const float fz = hb[8] * m0 + hb[9]  * m1 + hb[10] * m2 + hb[11];

    float d;
    if (sym) {
        float m = 3.4e38f;
        #pragma unroll
        for (int t = 0; t < NTS; ++t)
            m = fminf(m, wsmin[((size_t)(b * NTS + t)) * N + q]);
        const float c = fx * fx + fy * fy + fz * fz;
        d = sqrtf(fmaxf(0.0f, c + m));
    } else {
        const float dx = fx - tb[q * 3 + 0];
        const float dy = fy - tb[q * 3 + 1];
        const float dz = fz - tb[q * 3 + 2];
        d = sqrtf(dx * dx + dy * dy + dz * dz);
    }

    #pragma unroll
    for (int off = 32; off > 0; off >>= 1) d += __shfl_down(d, off);
    if (lane == 0) ps[wave] = d;
    __syncthreads();
    if (tid == 0) ws2[bid] = ps[0] + ps[1] + ps[2] + ps[3];
}

// K3: tiny deterministic finish: out[b] = mean over the batch's 8 partials.
__global__ __launch_bounds__(64) void addsloss_k3(
    const float* __restrict__ ws2, float* __restrict__ out)
{
    const int b = threadIdx.x;
    if (b < BS) {
        float s = 0.0f;
        #pragma unroll
        for (int p = 0; p < 8; ++p) s += ws2[b * 8 + p];
        out[b] = s * (1.0f / (float)N);
    }
}

extern "C" void kernel_launch(void* const* d_in, const int* in_sizes, int n_in,
                              void* d_out, int out_size, void* d_ws, size_t ws_size,
                              hipStream_t stream) {
    const float* target = (const float*)d_in[0];   // [16, 2048, 3]
    const float* mp     = (const float*)d_in[1];   // [16, 2048, 3]
    const int*   idx    = (const int*)  d_in[2];   // [16, 1]
    const float* H      = (const float*)d_in[3];   // [16, 4, 4]
    float*       out    = (float*)d_out;           // [16]
    float*       wsmin  = (float*)d_ws;            // BS*NTS*N floats = 4 MB
    float*       ws2    = wsmin + (size_t)BS * NTS * N;  // 128 partials

    addsloss_k1<<<BS * NQG * NTS, TPB, 0, stream>>>(target, mp, idx, H, wsmin);
    addsloss_k2<<<BS * 8, 256, 0, stream>>>(target, mp, idx, H, wsmin, ws2);
    addsloss_k3<<<1, 64, 0, stream>>>(ws2, out);
}